// Round 5
// baseline (204.364 us; speedup 1.0000x reference)
//
#include <hip/hip_runtime.h>

#define D     512
#define NB1   256
#define NB2   512
#define LOG2E 1.44269504088896f

typedef unsigned int   uint_t;
typedef unsigned short ushort_t;

struct alignas(16) F4 { float c[4]; };

__device__ __forceinline__ float bflo(uint_t u) { return __uint_as_float(u << 16); }
__device__ __forceinline__ float bfhi(uint_t u) { return __uint_as_float(u & 0xffff0000u); }
__device__ __forceinline__ ushort_t f2bf(float f) {
    uint_t u = __float_as_uint(f);
    u += 0x7fffu + ((u >> 16) & 1u);   // RNE
    return (ushort_t)(u >> 16);
}

// DPP cross-lane float add helper (ctrl must be a literal)
#define DPPF(v, ctrl) __int_as_float(__builtin_amdgcn_update_dpp(0, __float_as_int(v), ctrl, 0xf, 0xf, true))

// ================= merged prep kernel =================
__global__ __launch_bounds__(256) void prep_kernel(
    const float* __restrict__ emb1, const float* __restrict__ emb2,
    const float* __restrict__ cert2, const float* __restrict__ links,
    float* __restrict__ n1, ushort_t* __restrict__ n2h, ushort_t* __restrict__ c2h,
    uint_t* __restrict__ pidx, float* __restrict__ wval)
{
    const int blk  = blockIdx.x;
    const int lane = threadIdx.x & 63;
    const int w    = threadIdx.x >> 6;

    if (blk < 192) {                       // ---- normalize emb1 -> f32
        int row = blk * 4 + w;
        const float* r = emb1 + (size_t)row * D;
        float v[8]; float s = 0.f;
#pragma unroll
        for (int i = 0; i < 8; ++i) { v[i] = r[i * 64 + lane]; s += v[i] * v[i]; }
#pragma unroll
        for (int off = 32; off; off >>= 1) s += __shfl_xor(s, off);
        float inv = 1.f / fmaxf(sqrtf(s), 1e-12f);
        float* o = n1 + (size_t)row * D;
#pragma unroll
        for (int i = 0; i < 8; ++i) o[i * 64 + lane] = v[i] * inv;
    } else if (blk < 576) {                // ---- normalize emb2 -> bf16
        int row = (blk - 192) * 4 + w;
        const float* r = emb2 + (size_t)row * D;
        float v[8]; float s = 0.f;
#pragma unroll
        for (int i = 0; i < 8; ++i) { v[i] = r[i * 64 + lane]; s += v[i] * v[i]; }
#pragma unroll
        for (int off = 32; off; off >>= 1) s += __shfl_xor(s, off);
        float inv = 1.f / fmaxf(sqrtf(s), 1e-12f);
        ushort_t* o = n2h + (size_t)row * D;
#pragma unroll
        for (int i = 0; i < 8; ++i) o[i * 64 + lane] = f2bf(v[i] * inv);
    } else if (blk < 1088) {               // ---- cert2 layers 1,2 -> bf16
        int t = (blk - 576) * 256 + threadIdx.x;
        const float* s4 = cert2 + (size_t)NB2 * D + (size_t)t * 4;
        float4 v = *(const float4*)s4;
        uint2 o;
        o.x = (uint_t)f2bf(v.x) | ((uint_t)f2bf(v.y) << 16);
        o.y = (uint_t)f2bf(v.z) | ((uint_t)f2bf(v.w) << 16);
        *(uint2*)(c2h + (size_t)t * 4) = o;
    } else {                               // ---- top-3 per column
        int gw = (blk - 1088) * 4 + w;     // l*512 + e
        int l = gw >> 9;
        int e = gw & (D - 1);
        const float* base = links + (size_t)l * D * D + e;
        float v[8];
#pragma unroll
        for (int i = 0; i < 8; ++i) v[i] = base[(size_t)(i * 64 + lane) * D];
        float mv[3]; int mi[3];
        for (int k = 0; k < 3; ++k) {
            float lm = -1.f; int li = 0x7fffffff;
#pragma unroll
            for (int i = 0; i < 8; ++i)
                if (v[i] > lm) { lm = v[i]; li = i * 64 + lane; }
#pragma unroll
            for (int off = 32; off; off >>= 1) {
                float ov = __shfl_xor(lm, off);
                int oi = __shfl_xor(li, off);
                if (ov > lm || (ov == lm && oi < li)) { lm = ov; li = oi; }
            }
            mv[k] = lm; mi[k] = li;
            if (li < D && (li & 63) == lane) v[li >> 6] = -1.f;
        }
        if (lane == 0) {
            float invs = 1.f / (mv[0] + mv[1] + mv[2] + 1e-8f);
            uint_t f0 = (uint_t)mi[0] ^ (((uint_t)mi[0] >> 3) & 7u);
            uint_t f1 = (uint_t)mi[1] ^ (((uint_t)mi[1] >> 3) & 7u);
            uint_t f2 = (uint_t)mi[2] ^ (((uint_t)mi[2] >> 3) & 7u);
            pidx[gw] = f0 | (f1 << 9) | (f2 << 18);
            wval[(l * 3 + 0) * D + e] = mv[0] * invs;
            wval[(l * 3 + 1) * D + e] = mv[1] * invs;
            wval[(l * 3 + 2) * D + e] = mv[2] * invs;
        }
    }
}

// ================= gather-triple bank balance =================
// For each (layer, wave, parity): 64 e's, each with 3 (slot,weight) pairs.
// Greedily permute each triple so each gather position's 64 slots spread
// evenly over the 8 LDS bank-groups (slot & 7). In-place rewrite.
__global__ __launch_bounds__(64) void balance_kernel(uint_t* __restrict__ pidx,
                                                     float* __restrict__ wval) {
    int t = threadIdx.x;   // 16 active threads
    if (t >= 16) return;
    int l   = t >> 3;
    int w   = (t >> 1) & 3;
    int par = t & 1;
    int cnt[3][8];
#pragma unroll
    for (int i = 0; i < 3; ++i)
#pragma unroll
        for (int g = 0; g < 8; ++g) cnt[i][g] = 0;
    const int perms[6][3] = {{0,1,2},{0,2,1},{1,0,2},{1,2,0},{2,0,1},{2,1,0}};
    for (int j = 0; j < 64; ++j) {
        int e = w * 128 + par + j * 2;
        uint_t p = pidx[l * D + e];
        uint_t s[3] = { p & 511u, (p >> 9) & 511u, (p >> 18) & 511u };
        float wv[3] = { wval[(l*3+0)*D+e], wval[(l*3+1)*D+e], wval[(l*3+2)*D+e] };
        int best = 0, bc = 0x7fffffff;
        for (int q = 0; q < 6; ++q) {
            int c = cnt[0][s[perms[q][0]] & 7] +
                    cnt[1][s[perms[q][1]] & 7] +
                    cnt[2][s[perms[q][2]] & 7];
            if (c < bc) { bc = c; best = q; }
        }
        uint_t s0 = s[perms[best][0]], s1 = s[perms[best][1]], s2 = s[perms[best][2]];
        cnt[0][s0 & 7]++; cnt[1][s1 & 7]++; cnt[2][s2 & 7]++;
        pidx[l * D + e] = s0 | (s1 << 9) | (s2 << 18);
        wval[(l*3+0)*D+e] = wv[perms[best][0]];
        wval[(l*3+1)*D+e] = wv[perms[best][1]];
        wval[(l*3+2)*D+e] = wv[perms[best][2]];
    }
}

// ================= fused main kernel =================
// block = (b, 32 n's); 4 waves split e; n batched by 4; 2-phase pipelined.
__global__ __launch_bounds__(256, 6) void avsl_main_kernel(
    const float* __restrict__ n1,      // (3,B1,D) f32 normalized emb1
    const ushort_t* __restrict__ n2h,  // (3,B2,D) bf16 normalized emb2
    const float* __restrict__ cert1,   // (3,B1,D) f32
    const ushort_t* __restrict__ c2h,  // (2,B2,D) bf16 cert2 layers 1,2
    const uint_t* __restrict__ pidx,   // (2,D) phi-swizzled, bank-balanced indices
    const float* __restrict__ wval,    // (2,3,D) matched weights
    const float* __restrict__ alpha,   // (2,D)
    const float* __restrict__ beta,    // (2,D)
    float* __restrict__ out)           // (B1,B2)
{
    __shared__ F4 vbuf[3 * D];         // [0..511]=v0 ping, [512..1023]=v0 pong, [1024..1535]=v1
    __shared__ float pbuf[16];
    const int tid  = threadIdx.x;
    const int lane = tid & 63;
    const int wid  = tid >> 6;
    const int b    = blockIdx.x >> 4;
    const int n0   = (blockIdx.x & 15) * 32;
    const int e0   = wid * 128 + lane * 2;     // lane owns e0, e0+1

    // ---- persistent per-e tables
    float2 a0  = *(const float2*)(n1 + (size_t)(0 * NB1 + b) * D + e0);
    float2 a1  = *(const float2*)(n1 + (size_t)(1 * NB1 + b) * D + e0);
    float2 a2  = *(const float2*)(n1 + (size_t)(2 * NB1 + b) * D + e0);
    float2 al1 = *(const float2*)(alpha + e0);
    float2 al2 = *(const float2*)(alpha + D + e0);
    float2 c11 = *(const float2*)(cert1 + (size_t)(1 * NB1 + b) * D + e0);
    float2 c12 = *(const float2*)(cert1 + (size_t)(2 * NB1 + b) * D + e0);
    float2 be1 = *(const float2*)(beta + e0);
    float2 be2 = *(const float2*)(beta + D + e0);
    const float acn1x = -al1.x * c11.x * LOG2E, acn1y = -al1.y * c11.y * LOG2E;
    const float acn2x = -al2.x * c12.x * LOG2E, acn2y = -al2.y * c12.y * LOG2E;
    const float btn1x = -be1.x * LOG2E, btn1y = -be1.y * LOG2E;
    const float btn2x = -be2.x * LOG2E, btn2y = -be2.y * LOG2E;

    float w1v[3][2], w2v[3][2];
#pragma unroll
    for (int k = 0; k < 3; ++k) {
        float2 t1 = *(const float2*)(wval + k * D + e0);
        float2 t2 = *(const float2*)(wval + (3 + k) * D + e0);
        w1v[k][0] = t1.x; w1v[k][1] = t1.y;
        w2v[k][0] = t2.x; w2v[k][1] = t2.y;
    }
    uint2 p1 = *(const uint2*)(pidx + e0);
    uint2 p2 = *(const uint2*)(pidx + D + e0);

    // hoisted LDS gather pointers (parity handled via [512] imm offset)
    const F4* q1a0 = &vbuf[p1.x & 511u];
    const F4* q1b0 = &vbuf[(p1.x >> 9) & 511u];
    const F4* q1c0 = &vbuf[(p1.x >> 18) & 511u];
    const F4* q1a1 = &vbuf[p1.y & 511u];
    const F4* q1b1 = &vbuf[(p1.y >> 9) & 511u];
    const F4* q1c1 = &vbuf[(p1.y >> 18) & 511u];
    const F4* q2a0 = &vbuf[1024 + (p2.x & 511u)];
    const F4* q2b0 = &vbuf[1024 + ((p2.x >> 9) & 511u)];
    const F4* q2c0 = &vbuf[1024 + ((p2.x >> 18) & 511u)];
    const F4* q2a1 = &vbuf[1024 + (p2.y & 511u)];
    const F4* q2b1 = &vbuf[1024 + ((p2.y >> 9) & 511u)];
    const F4* q2c1 = &vbuf[1024 + ((p2.y >> 18) & 511u)];
    const int sl0 = e0 ^ ((e0 >> 3) & 7);
    const int sl1 = (e0 + 1) ^ (((e0 + 1) >> 3) & 7);
    F4* qw0a = &vbuf[sl0];
    F4* qw0b = &vbuf[sl1];
    F4* qw1a = &vbuf[1024 + sl0];
    F4* qw1b = &vbuf[1024 + sl1];

    // stream pointers (advanced 4 rows per group)
    const ushort_t* pr0 = n2h + (size_t)(0 * NB2 + n0) * D + e0;
    const ushort_t* pr1 = n2h + (size_t)(1 * NB2 + n0) * D + e0;
    const ushort_t* pr2 = n2h + (size_t)(2 * NB2 + n0) * D + e0;
    const ushort_t* pc1 = c2h + (size_t)(0 * NB2 + n0) * D + e0;
    const ushort_t* pc2 = c2h + (size_t)(1 * NB2 + n0) * D + e0;

    // ---- prologue: loads for g=0, L0(0) -> v0[ping]
    uint_t r1c[4], c1c[4], r0c[4];
#pragma unroll
    for (int nn = 0; nn < 4; ++nn) {
        r0c[nn] = *(const uint_t*)(pr0 + nn * D);
        r1c[nn] = *(const uint_t*)(pr1 + nn * D);
        c1c[nn] = *(const uint_t*)(pc1 + nn * D);
    }
    {
        F4 v0a, v0b;
#pragma unroll
        for (int nn = 0; nn < 4; ++nn) {
            float d0 = a0.x - bflo(r0c[nn]);
            float d1 = a0.y - bfhi(r0c[nn]);
            v0a.c[nn] = d0 * d0;
            v0b.c[nn] = d1 * d1;
        }
        qw0a[0] = v0a;
        qw0b[0] = v0b;
    }
    __syncthreads();

#pragma unroll 2
    for (int g = 0; g < 8; ++g) {
        // ================= phase A =================
        if (g) {
            if (tid < 4)
                out[(size_t)b * NB2 + n0 + (g - 1) * 4 + tid] =
                    pbuf[tid] + pbuf[4 + tid] + pbuf[8 + tid] + pbuf[12 + tid];
        }
        // issue: r0 for g+1, r2/c2 for this g (overreads at g=7 land in next layer: in-bounds)
        uint_t r0n[4], r2c[4], c2c[4];
#pragma unroll
        for (int nn = 0; nn < 4; ++nn) {
            r0n[nn] = *(const uint_t*)(pr0 + (4 + nn) * D);
            r2c[nn] = *(const uint_t*)(pr2 + nn * D);
            c2c[nn] = *(const uint_t*)(pc2 + nn * D);
        }
        // L1: gather v0[g&1], blend, write v1
        {
            F4 gA0 = q1a0[(g & 1) * 512], gB0 = q1b0[(g & 1) * 512], gC0 = q1c0[(g & 1) * 512];
            F4 gA1 = q1a1[(g & 1) * 512], gB1 = q1b1[(g & 1) * 512], gC1 = q1c1[(g & 1) * 512];
            F4 o0, o1;
#pragma unroll
            for (int nn = 0; nn < 4; ++nn) {
                float rl = bflo(r1c[nn]), rh = bfhi(r1c[nn]);
                float cl = bflo(c1c[nn]), ch = bfhi(c1c[nn]);
                float gs0 = fmaf(w1v[0][0], gA0.c[nn], fmaf(w1v[1][0], gB0.c[nn], w1v[2][0] * gC0.c[nn]));
                float gs1 = fmaf(w1v[0][1], gA1.c[nn], fmaf(w1v[1][1], gB1.c[nn], w1v[2][1] * gC1.c[nn]));
                float P0 = __builtin_amdgcn_rcpf(1.f + __builtin_amdgcn_exp2f(fmaf(acn1x, cl, btn1x)));
                float P1 = __builtin_amdgcn_rcpf(1.f + __builtin_amdgcn_exp2f(fmaf(acn1y, ch, btn1y)));
                float d0 = a1.x - rl, d1 = a1.y - rh;
                o0.c[nn] = gs0 + P0 * (d0 * d0 - gs0);
                o1.c[nn] = gs1 + P1 * (d1 * d1 - gs1);
            }
            qw1a[0] = o0;
            qw1b[0] = o1;
        }
        __syncthreads();

        // ================= phase B =================
        // issue: r1/c1 for g+1 (overread at g=7 in-bounds)
        uint_t r1n[4], c1n[4];
#pragma unroll
        for (int nn = 0; nn < 4; ++nn) {
            r1n[nn] = *(const uint_t*)(pr1 + (4 + nn) * D);
            c1n[nn] = *(const uint_t*)(pc1 + (4 + nn) * D);
        }
        // L2: gather v1, blend, accumulate
        F4 acc;
        {
            F4 gA0 = q2a0[0], gB0 = q2b0[0], gC0 = q2c0[0];
            F4 gA1 = q2a1[0], gB1 = q2b1[0], gC1 = q2c1[0];
#pragma unroll
            for (int nn = 0; nn < 4; ++nn) {
                float rl = bflo(r2c[nn]), rh = bfhi(r2c[nn]);
                float cl = bflo(c2c[nn]), ch = bfhi(c2c[nn]);
                float gs0 = fmaf(w2v[0][0], gA0.c[nn], fmaf(w2v[1][0], gB0.c[nn], w2v[2][0] * gC0.c[nn]));
                float gs1 = fmaf(w2v[0][1], gA1.c[nn], fmaf(w2v[1][1], gB1.c[nn], w2v[2][1] * gC1.c[nn]));
                float P0 = __builtin_amdgcn_rcpf(1.f + __builtin_amdgcn_exp2f(fmaf(acn2x, cl, btn2x)));
                float P1 = __builtin_amdgcn_rcpf(1.f + __builtin_amdgcn_exp2f(fmaf(acn2y, ch, btn2y)));
                float d0 = a2.x - rl, d1 = a2.y - rh;
                acc.c[nn] = (gs0 + P0 * (d0 * d0 - gs0)) + (gs1 + P1 * (d1 * d1 - gs1));
            }
        }
        // L0 for g+1 -> v0[(g+1)&1]
        {
            F4 v0a, v0b;
#pragma unroll
            for (int nn = 0; nn < 4; ++nn) {
                float d0 = a0.x - bflo(r0n[nn]);
                float d1 = a0.y - bfhi(r0n[nn]);
                v0a.c[nn] = d0 * d0;
                v0b.c[nn] = d1 * d1;
            }
            qw0a[((g + 1) & 1) * 512] = v0a;
            qw0b[((g + 1) & 1) * 512] = v0b;
        }
        // wave reduction: DPP split butterfly (VALU) + xor16 swizzle + xor32
        {
            float c0 = acc.c[0], c1 = acc.c[1], c2 = acc.c[2], c3 = acc.c[3];
            float pA = DPPF(c0, 0xB1);   // quad_perm [1,0,3,2]  (xor 1)
            float pB = DPPF(c1, 0xB1);
            float pC = DPPF(c2, 0xB1);
            float pD = DPPF(c3, 0xB1);
            float u0, u1;
            if (lane & 1) { u0 = c1 + pB; u1 = c3 + pD; }
            else          { u0 = c0 + pA; u1 = c2 + pC; }
            float q0 = DPPF(u0, 0x4E);   // quad_perm [2,3,0,1]  (xor 2)
            float q1 = DPPF(u1, 0x4E);
            float v = (lane & 2) ? (u1 + q1) : (u0 + q0);   // holds nn = lane&3
            v += DPPF(v, 0x124);          // row_ror:4
            v += DPPF(v, 0x128);          // row_ror:8
            v += __int_as_float(__builtin_amdgcn_ds_swizzle(__float_as_int(v), 0x401F)); // xor 16
            v += __shfl_xor(v, 32);
            if (lane < 4) pbuf[wid * 4 + lane] = v;
        }
        __syncthreads();

        // rotate prefetched data / advance pointers
#pragma unroll
        for (int nn = 0; nn < 4; ++nn) { r1c[nn] = r1n[nn]; c1c[nn] = c1n[nn]; }
        pr0 += 4 * D; pr1 += 4 * D; pr2 += 4 * D; pc1 += 4 * D; pc2 += 4 * D;
    }

    // epilogue: out-write for g=7
    if (tid < 4)
        out[(size_t)b * NB2 + n0 + 28 + tid] =
            pbuf[tid] + pbuf[4 + tid] + pbuf[8 + tid] + pbuf[12 + tid];
}

extern "C" void kernel_launch(void* const* d_in, const int* in_sizes, int n_in,
                              void* d_out, int out_size, void* d_ws, size_t ws_size,
                              hipStream_t stream) {
    const float* emb1  = (const float*)d_in[0];  // (3,256,512)
    const float* cert1 = (const float*)d_in[1];  // (3,256,512)
    const float* emb2  = (const float*)d_in[2];  // (3,512,512)
    const float* cert2 = (const float*)d_in[3];  // (3,512,512)
    const float* links = (const float*)d_in[4];  // (2,512,512)
    const float* alpha = (const float*)d_in[5];  // (2,512)
    const float* beta  = (const float*)d_in[6];  // (2,512)
    float* out = (float*)d_out;                  // (256,512)

    float* n1      = (float*)d_ws;                      // 3*256*512 f32
    ushort_t* n2h  = (ushort_t*)(n1 + 3 * NB1 * D);     // 3*512*512 bf16
    ushort_t* c2h  = n2h + 3 * NB2 * D;                 // 2*512*512 bf16
    uint_t* pidx   = (uint_t*)(c2h + 2 * NB2 * D);      // 2*512 u32
    float* wval    = (float*)(pidx + 2 * D);            // 2*3*512 f32

    hipLaunchKernelGGL(prep_kernel, dim3(1344), dim3(256), 0, stream,
                       emb1, emb2, cert2, links, n1, n2h, c2h, pidx, wval);
    hipLaunchKernelGGL(balance_kernel, dim3(1), dim3(64), 0, stream, pidx, wval);
    hipLaunchKernelGGL(avsl_main_kernel, dim3(4096), dim3(256), 0, stream,
                       n1, n2h, cert1, c2h, pidx, wval, alpha, beta, out);
}

// Round 6
// 193.378 us; speedup vs baseline: 1.0568x; 1.0568x over previous
//
#include <hip/hip_runtime.h>

#define D     512
#define NB1   256
#define NB2   512
#define LOG2E 1.44269504088896f

typedef unsigned int   uint_t;
typedef unsigned short ushort_t;

struct alignas(16) F4 { float c[4]; };

__device__ __forceinline__ float bflo(uint_t u) { return __uint_as_float(u << 16); }
__device__ __forceinline__ float bfhi(uint_t u) { return __uint_as_float(u & 0xffff0000u); }
__device__ __forceinline__ ushort_t f2bf(float f) {
    uint_t u = __float_as_uint(f);
    u += 0x7fffu + ((u >> 16) & 1u);   // RNE
    return (ushort_t)(u >> 16);
}

// DPP cross-lane float add helper (ctrl must be a literal)
#define DPPF(v, ctrl) __int_as_float(__builtin_amdgcn_update_dpp(0, __float_as_int(v), ctrl, 0xf, 0xf, true))

// ================= merged prep kernel =================
__global__ __launch_bounds__(256) void prep_kernel(
    const float* __restrict__ emb1, const float* __restrict__ emb2,
    const float* __restrict__ cert2, const float* __restrict__ links,
    float* __restrict__ n1, ushort_t* __restrict__ n2h, ushort_t* __restrict__ c2h,
    uint_t* __restrict__ pidx, float* __restrict__ wval)
{
    const int blk  = blockIdx.x;
    const int lane = threadIdx.x & 63;
    const int w    = threadIdx.x >> 6;

    if (blk < 192) {                       // ---- normalize emb1 -> f32
        int row = blk * 4 + w;
        const float* r = emb1 + (size_t)row * D;
        float v[8]; float s = 0.f;
#pragma unroll
        for (int i = 0; i < 8; ++i) { v[i] = r[i * 64 + lane]; s += v[i] * v[i]; }
#pragma unroll
        for (int off = 32; off; off >>= 1) s += __shfl_xor(s, off);
        float inv = 1.f / fmaxf(sqrtf(s), 1e-12f);
        float* o = n1 + (size_t)row * D;
#pragma unroll
        for (int i = 0; i < 8; ++i) o[i * 64 + lane] = v[i] * inv;
    } else if (blk < 576) {                // ---- normalize emb2 -> bf16
        int row = (blk - 192) * 4 + w;
        const float* r = emb2 + (size_t)row * D;
        float v[8]; float s = 0.f;
#pragma unroll
        for (int i = 0; i < 8; ++i) { v[i] = r[i * 64 + lane]; s += v[i] * v[i]; }
#pragma unroll
        for (int off = 32; off; off >>= 1) s += __shfl_xor(s, off);
        float inv = 1.f / fmaxf(sqrtf(s), 1e-12f);
        ushort_t* o = n2h + (size_t)row * D;
#pragma unroll
        for (int i = 0; i < 8; ++i) o[i * 64 + lane] = f2bf(v[i] * inv);
    } else if (blk < 1088) {               // ---- cert2 layers 1,2 -> bf16
        int t = (blk - 576) * 256 + threadIdx.x;
        const float* s4 = cert2 + (size_t)NB2 * D + (size_t)t * 4;
        float4 v = *(const float4*)s4;
        uint2 o;
        o.x = (uint_t)f2bf(v.x) | ((uint_t)f2bf(v.y) << 16);
        o.y = (uint_t)f2bf(v.z) | ((uint_t)f2bf(v.w) << 16);
        *(uint2*)(c2h + (size_t)t * 4) = o;
    } else {                               // ---- top-3 per column
        int gw = (blk - 1088) * 4 + w;     // l*512 + e
        int l = gw >> 9;
        int e = gw & (D - 1);
        const float* base = links + (size_t)l * D * D + e;
        float v[8];
#pragma unroll
        for (int i = 0; i < 8; ++i) v[i] = base[(size_t)(i * 64 + lane) * D];
        float mv[3]; int mi[3];
        for (int k = 0; k < 3; ++k) {
            float lm = -1.f; int li = 0x7fffffff;
#pragma unroll
            for (int i = 0; i < 8; ++i)
                if (v[i] > lm) { lm = v[i]; li = i * 64 + lane; }
#pragma unroll
            for (int off = 32; off; off >>= 1) {
                float ov = __shfl_xor(lm, off);
                int oi = __shfl_xor(li, off);
                if (ov > lm || (ov == lm && oi < li)) { lm = ov; li = oi; }
            }
            mv[k] = lm; mi[k] = li;
            if (li < D && (li & 63) == lane) v[li >> 6] = -1.f;
        }
        if (lane == 0) {
            float invs = 1.f / (mv[0] + mv[1] + mv[2] + 1e-8f);
            uint_t f0 = (uint_t)mi[0] ^ (((uint_t)mi[0] >> 3) & 7u);
            uint_t f1 = (uint_t)mi[1] ^ (((uint_t)mi[1] >> 3) & 7u);
            uint_t f2 = (uint_t)mi[2] ^ (((uint_t)mi[2] >> 3) & 7u);
            pidx[gw] = f0 | (f1 << 9) | (f2 << 18);
            wval[(l * 3 + 0) * D + e] = mv[0] * invs;
            wval[(l * 3 + 1) * D + e] = mv[1] * invs;
            wval[(l * 3 + 2) * D + e] = mv[2] * invs;
        }
    }
}

// ================= gather-triple bank balance (LDS-staged) =================
// Load all pidx (1024 u32) + wval (3072 f32) into LDS cooperatively, run the
// 16 independent greedy chains from LDS, write back vectorized.
__global__ __launch_bounds__(256) void balance_kernel(uint_t* __restrict__ pidx,
                                                      float* __restrict__ wval) {
    __shared__ uint_t sp[2 * D];          // 4 KB
    __shared__ float  sw[6 * D];          // 12 KB
    const int tid = threadIdx.x;

    // cooperative load: 1024 u32 (4/thread), 3072 f32 (12/thread)
    {
        uint4 v = *(const uint4*)(pidx + tid * 4);
        *(uint4*)(sp + tid * 4) = v;
#pragma unroll
        for (int k = 0; k < 3; ++k) {
            float4 f = *(const float4*)(wval + k * 1024 + tid * 4);
            *(float4*)(sw + k * 1024 + tid * 4) = f;
        }
    }
    __syncthreads();

    if (tid < 16) {
        const int l   = tid >> 3;
        const int w   = (tid >> 1) & 3;
        const int par = tid & 1;
        int cnt[3][8];
#pragma unroll
        for (int i = 0; i < 3; ++i)
#pragma unroll
            for (int g = 0; g < 8; ++g) cnt[i][g] = 0;
        const int perms[6][3] = {{0,1,2},{0,2,1},{1,0,2},{1,2,0},{2,0,1},{2,1,0}};
        for (int j = 0; j < 64; ++j) {
            int e = w * 128 + par + j * 2;
            uint_t p = sp[l * D + e];
            uint_t s[3] = { p & 511u, (p >> 9) & 511u, (p >> 18) & 511u };
            float wv[3] = { sw[(l*3+0)*D+e], sw[(l*3+1)*D+e], sw[(l*3+2)*D+e] };
            int best = 0, bc = 0x7fffffff;
#pragma unroll
            for (int q = 0; q < 6; ++q) {
                int c = cnt[0][s[perms[q][0]] & 7] +
                        cnt[1][s[perms[q][1]] & 7] +
                        cnt[2][s[perms[q][2]] & 7];
                if (c < bc) { bc = c; best = q; }
            }
            uint_t s0 = s[perms[best][0]], s1 = s[perms[best][1]], s2 = s[perms[best][2]];
            cnt[0][s0 & 7]++; cnt[1][s1 & 7]++; cnt[2][s2 & 7]++;
            sp[l * D + e] = s0 | (s1 << 9) | (s2 << 18);
            sw[(l*3+0)*D+e] = wv[perms[best][0]];
            sw[(l*3+1)*D+e] = wv[perms[best][1]];
            sw[(l*3+2)*D+e] = wv[perms[best][2]];
        }
    }
    __syncthreads();

    // cooperative store back
    {
        uint4 v = *(const uint4*)(sp + tid * 4);
        *(uint4*)(pidx + tid * 4) = v;
#pragma unroll
        for (int k = 0; k < 3; ++k) {
            float4 f = *(const float4*)(sw + k * 1024 + tid * 4);
            *(float4*)(wval + k * 1024 + tid * 4) = f;
        }
    }
}

// ================= fused main kernel =================
// block = (b, 32 n's); 4 waves split e; n batched by 4; 2-phase pipelined.
__global__ __launch_bounds__(256, 6) void avsl_main_kernel(
    const float* __restrict__ n1,      // (3,B1,D) f32 normalized emb1
    const ushort_t* __restrict__ n2h,  // (3,B2,D) bf16 normalized emb2
    const float* __restrict__ cert1,   // (3,B1,D) f32
    const ushort_t* __restrict__ c2h,  // (2,B2,D) bf16 cert2 layers 1,2
    const uint_t* __restrict__ pidx,   // (2,D) phi-swizzled, bank-balanced indices
    const float* __restrict__ wval,    // (2,3,D) matched weights
    const float* __restrict__ alpha,   // (2,D)
    const float* __restrict__ beta,    // (2,D)
    float* __restrict__ out)           // (B1,B2)
{
    __shared__ F4 vbuf[3 * D];         // [0..511]=v0 ping, [512..1023]=v0 pong, [1024..1535]=v1
    __shared__ float pbuf[16];
    const int tid  = threadIdx.x;
    const int lane = tid & 63;
    const int wid  = tid >> 6;
    const int b    = blockIdx.x >> 4;
    const int n0   = (blockIdx.x & 15) * 32;
    const int e0   = wid * 128 + lane * 2;     // lane owns e0, e0+1

    // ---- persistent per-e tables
    float2 a0  = *(const float2*)(n1 + (size_t)(0 * NB1 + b) * D + e0);
    float2 a1  = *(const float2*)(n1 + (size_t)(1 * NB1 + b) * D + e0);
    float2 a2  = *(const float2*)(n1 + (size_t)(2 * NB1 + b) * D + e0);
    float2 al1 = *(const float2*)(alpha + e0);
    float2 al2 = *(const float2*)(alpha + D + e0);
    float2 c11 = *(const float2*)(cert1 + (size_t)(1 * NB1 + b) * D + e0);
    float2 c12 = *(const float2*)(cert1 + (size_t)(2 * NB1 + b) * D + e0);
    float2 be1 = *(const float2*)(beta + e0);
    float2 be2 = *(const float2*)(beta + D + e0);
    const float acn1x = -al1.x * c11.x * LOG2E, acn1y = -al1.y * c11.y * LOG2E;
    const float acn2x = -al2.x * c12.x * LOG2E, acn2y = -al2.y * c12.y * LOG2E;
    const float btn1x = -be1.x * LOG2E, btn1y = -be1.y * LOG2E;
    const float btn2x = -be2.x * LOG2E, btn2y = -be2.y * LOG2E;

    float w1v[3][2], w2v[3][2];
#pragma unroll
    for (int k = 0; k < 3; ++k) {
        float2 t1 = *(const float2*)(wval + k * D + e0);
        float2 t2 = *(const float2*)(wval + (3 + k) * D + e0);
        w1v[k][0] = t1.x; w1v[k][1] = t1.y;
        w2v[k][0] = t2.x; w2v[k][1] = t2.y;
    }
    uint2 p1 = *(const uint2*)(pidx + e0);
    uint2 p2 = *(const uint2*)(pidx + D + e0);

    // hoisted LDS gather pointers (parity handled via [512] imm offset)
    const F4* q1a0 = &vbuf[p1.x & 511u];
    const F4* q1b0 = &vbuf[(p1.x >> 9) & 511u];
    const F4* q1c0 = &vbuf[(p1.x >> 18) & 511u];
    const F4* q1a1 = &vbuf[p1.y & 511u];
    const F4* q1b1 = &vbuf[(p1.y >> 9) & 511u];
    const F4* q1c1 = &vbuf[(p1.y >> 18) & 511u];
    const F4* q2a0 = &vbuf[1024 + (p2.x & 511u)];
    const F4* q2b0 = &vbuf[1024 + ((p2.x >> 9) & 511u)];
    const F4* q2c0 = &vbuf[1024 + ((p2.x >> 18) & 511u)];
    const F4* q2a1 = &vbuf[1024 + (p2.y & 511u)];
    const F4* q2b1 = &vbuf[1024 + ((p2.y >> 9) & 511u)];
    const F4* q2c1 = &vbuf[1024 + ((p2.y >> 18) & 511u)];
    const int sl0 = e0 ^ ((e0 >> 3) & 7);
    const int sl1 = (e0 + 1) ^ (((e0 + 1) >> 3) & 7);
    F4* qw0a = &vbuf[sl0];
    F4* qw0b = &vbuf[sl1];
    F4* qw1a = &vbuf[1024 + sl0];
    F4* qw1b = &vbuf[1024 + sl1];

    // stream pointers (advanced 4 rows per group)
    const ushort_t* pr0 = n2h + (size_t)(0 * NB2 + n0) * D + e0;
    const ushort_t* pr1 = n2h + (size_t)(1 * NB2 + n0) * D + e0;
    const ushort_t* pr2 = n2h + (size_t)(2 * NB2 + n0) * D + e0;
    const ushort_t* pc1 = c2h + (size_t)(0 * NB2 + n0) * D + e0;
    const ushort_t* pc2 = c2h + (size_t)(1 * NB2 + n0) * D + e0;

    // ---- prologue: loads for g=0, L0(0) -> v0[ping]
    uint_t r1c[4], c1c[4], r0c[4];
#pragma unroll
    for (int nn = 0; nn < 4; ++nn) {
        r0c[nn] = *(const uint_t*)(pr0 + nn * D);
        r1c[nn] = *(const uint_t*)(pr1 + nn * D);
        c1c[nn] = *(const uint_t*)(pc1 + nn * D);
    }
    {
        F4 v0a, v0b;
#pragma unroll
        for (int nn = 0; nn < 4; ++nn) {
            float d0 = a0.x - bflo(r0c[nn]);
            float d1 = a0.y - bfhi(r0c[nn]);
            v0a.c[nn] = d0 * d0;
            v0b.c[nn] = d1 * d1;
        }
        qw0a[0] = v0a;
        qw0b[0] = v0b;
    }
    __syncthreads();

#pragma unroll 2
    for (int g = 0; g < 8; ++g) {
        // ================= phase A =================
        if (g) {
            if (tid < 4)
                out[(size_t)b * NB2 + n0 + (g - 1) * 4 + tid] =
                    pbuf[tid] + pbuf[4 + tid] + pbuf[8 + tid] + pbuf[12 + tid];
        }
        // issue: r0 for g+1, r2/c2 for this g (overreads at g=7 land in next layer: in-bounds)
        uint_t r0n[4], r2c[4], c2c[4];
#pragma unroll
        for (int nn = 0; nn < 4; ++nn) {
            r0n[nn] = *(const uint_t*)(pr0 + (4 + nn) * D);
            r2c[nn] = *(const uint_t*)(pr2 + nn * D);
            c2c[nn] = *(const uint_t*)(pc2 + nn * D);
        }
        // L1: gather v0[g&1], blend, write v1
        {
            F4 gA0 = q1a0[(g & 1) * 512], gB0 = q1b0[(g & 1) * 512], gC0 = q1c0[(g & 1) * 512];
            F4 gA1 = q1a1[(g & 1) * 512], gB1 = q1b1[(g & 1) * 512], gC1 = q1c1[(g & 1) * 512];
            F4 o0, o1;
#pragma unroll
            for (int nn = 0; nn < 4; ++nn) {
                float rl = bflo(r1c[nn]), rh = bfhi(r1c[nn]);
                float cl = bflo(c1c[nn]), ch = bfhi(c1c[nn]);
                float gs0 = fmaf(w1v[0][0], gA0.c[nn], fmaf(w1v[1][0], gB0.c[nn], w1v[2][0] * gC0.c[nn]));
                float gs1 = fmaf(w1v[0][1], gA1.c[nn], fmaf(w1v[1][1], gB1.c[nn], w1v[2][1] * gC1.c[nn]));
                float P0 = __builtin_amdgcn_rcpf(1.f + __builtin_amdgcn_exp2f(fmaf(acn1x, cl, btn1x)));
                float P1 = __builtin_amdgcn_rcpf(1.f + __builtin_amdgcn_exp2f(fmaf(acn1y, ch, btn1y)));
                float d0 = a1.x - rl, d1 = a1.y - rh;
                o0.c[nn] = gs0 + P0 * (d0 * d0 - gs0);
                o1.c[nn] = gs1 + P1 * (d1 * d1 - gs1);
            }
            qw1a[0] = o0;
            qw1b[0] = o1;
        }
        __syncthreads();

        // ================= phase B =================
        // issue: r1/c1 for g+1 (overread at g=7 in-bounds)
        uint_t r1n[4], c1n[4];
#pragma unroll
        for (int nn = 0; nn < 4; ++nn) {
            r1n[nn] = *(const uint_t*)(pr1 + (4 + nn) * D);
            c1n[nn] = *(const uint_t*)(pc1 + (4 + nn) * D);
        }
        // L2: gather v1, blend, accumulate
        F4 acc;
        {
            F4 gA0 = q2a0[0], gB0 = q2b0[0], gC0 = q2c0[0];
            F4 gA1 = q2a1[0], gB1 = q2b1[0], gC1 = q2c1[0];
#pragma unroll
            for (int nn = 0; nn < 4; ++nn) {
                float rl = bflo(r2c[nn]), rh = bfhi(r2c[nn]);
                float cl = bflo(c2c[nn]), ch = bfhi(c2c[nn]);
                float gs0 = fmaf(w2v[0][0], gA0.c[nn], fmaf(w2v[1][0], gB0.c[nn], w2v[2][0] * gC0.c[nn]));
                float gs1 = fmaf(w2v[0][1], gA1.c[nn], fmaf(w2v[1][1], gB1.c[nn], w2v[2][1] * gC1.c[nn]));
                float P0 = __builtin_amdgcn_rcpf(1.f + __builtin_amdgcn_exp2f(fmaf(acn2x, cl, btn2x)));
                float P1 = __builtin_amdgcn_rcpf(1.f + __builtin_amdgcn_exp2f(fmaf(acn2y, ch, btn2y)));
                float d0 = a2.x - rl, d1 = a2.y - rh;
                acc.c[nn] = (gs0 + P0 * (d0 * d0 - gs0)) + (gs1 + P1 * (d1 * d1 - gs1));
            }
        }
        // L0 for g+1 -> v0[(g+1)&1]
        {
            F4 v0a, v0b;
#pragma unroll
            for (int nn = 0; nn < 4; ++nn) {
                float d0 = a0.x - bflo(r0n[nn]);
                float d1 = a0.y - bfhi(r0n[nn]);
                v0a.c[nn] = d0 * d0;
                v0b.c[nn] = d1 * d1;
            }
            qw0a[((g + 1) & 1) * 512] = v0a;
            qw0b[((g + 1) & 1) * 512] = v0b;
        }
        // wave reduction: DPP split butterfly (VALU) + xor16 swizzle + xor32
        {
            float c0 = acc.c[0], c1 = acc.c[1], c2 = acc.c[2], c3 = acc.c[3];
            float pA = DPPF(c0, 0xB1);   // quad_perm [1,0,3,2]  (xor 1)
            float pB = DPPF(c1, 0xB1);
            float pC = DPPF(c2, 0xB1);
            float pD = DPPF(c3, 0xB1);
            float u0, u1;
            if (lane & 1) { u0 = c1 + pB; u1 = c3 + pD; }
            else          { u0 = c0 + pA; u1 = c2 + pC; }
            float q0 = DPPF(u0, 0x4E);   // quad_perm [2,3,0,1]  (xor 2)
            float q1 = DPPF(u1, 0x4E);
            float v = (lane & 2) ? (u1 + q1) : (u0 + q0);   // holds nn = lane&3
            v += DPPF(v, 0x124);          // row_ror:4
            v += DPPF(v, 0x128);          // row_ror:8
            v += __int_as_float(__builtin_amdgcn_ds_swizzle(__float_as_int(v), 0x401F)); // xor 16
            v += __shfl_xor(v, 32);
            if (lane < 4) pbuf[wid * 4 + lane] = v;
        }
        __syncthreads();

        // rotate prefetched data / advance pointers
#pragma unroll
        for (int nn = 0; nn < 4; ++nn) { r1c[nn] = r1n[nn]; c1c[nn] = c1n[nn]; }
        pr0 += 4 * D; pr1 += 4 * D; pr2 += 4 * D; pc1 += 4 * D; pc2 += 4 * D;
    }

    // epilogue: out-write for g=7
    if (tid < 4)
        out[(size_t)b * NB2 + n0 + 28 + tid] =
            pbuf[tid] + pbuf[4 + tid] + pbuf[8 + tid] + pbuf[12 + tid];
}

extern "C" void kernel_launch(void* const* d_in, const int* in_sizes, int n_in,
                              void* d_out, int out_size, void* d_ws, size_t ws_size,
                              hipStream_t stream) {
    const float* emb1  = (const float*)d_in[0];  // (3,256,512)
    const float* cert1 = (const float*)d_in[1];  // (3,256,512)
    const float* emb2  = (const float*)d_in[2];  // (3,512,512)
    const float* cert2 = (const float*)d_in[3];  // (3,512,512)
    const float* links = (const float*)d_in[4];  // (2,512,512)
    const float* alpha = (const float*)d_in[5];  // (2,512)
    const float* beta  = (const float*)d_in[6];  // (2,512)
    float* out = (float*)d_out;                  // (256,512)

    float* n1      = (float*)d_ws;                      // 3*256*512 f32
    ushort_t* n2h  = (ushort_t*)(n1 + 3 * NB1 * D);     // 3*512*512 bf16
    ushort_t* c2h  = n2h + 3 * NB2 * D;                 // 2*512*512 bf16
    uint_t* pidx   = (uint_t*)(c2h + 2 * NB2 * D);      // 2*512 u32
    float* wval    = (float*)(pidx + 2 * D);            // 2*3*512 f32

    hipLaunchKernelGGL(prep_kernel, dim3(1344), dim3(256), 0, stream,
                       emb1, emb2, cert2, links, n1, n2h, c2h, pidx, wval);
    hipLaunchKernelGGL(balance_kernel, dim3(1), dim3(256), 0, stream, pidx, wval);
    hipLaunchKernelGGL(avsl_main_kernel, dim3(4096), dim3(256), 0, stream,
                       n1, n2h, cert1, c2h, pidx, wval, alpha, beta, out);
}

// Round 7
// 105.529 us; speedup vs baseline: 1.9366x; 1.8325x over previous
//
#include <hip/hip_runtime.h>

#define D     512
#define NB1   256
#define NB2   512
#define LOG2E 1.44269504088896f

typedef unsigned int   uint_t;
typedef unsigned short ushort_t;

struct alignas(16) F4 { float c[4]; };

__device__ __forceinline__ float bflo(uint_t u) { return __uint_as_float(u << 16); }
__device__ __forceinline__ float bfhi(uint_t u) { return __uint_as_float(u & 0xffff0000u); }
__device__ __forceinline__ ushort_t f2bf(float f) {
    uint_t u = __float_as_uint(f);
    u += 0x7fffu + ((u >> 16) & 1u);   // RNE
    return (ushort_t)(u >> 16);
}

// DPP cross-lane float add helper (ctrl must be a literal)
#define DPPF(v, ctrl) __int_as_float(__builtin_amdgcn_update_dpp(0, __float_as_int(v), ctrl, 0xf, 0xf, true))

// ================= merged prep kernel =================
__global__ __launch_bounds__(256) void prep_kernel(
    const float* __restrict__ emb1, const float* __restrict__ emb2,
    const float* __restrict__ cert2, const float* __restrict__ links,
    float* __restrict__ n1, ushort_t* __restrict__ n2h, ushort_t* __restrict__ c2h,
    uint_t* __restrict__ pidx, float* __restrict__ wval)
{
    const int blk  = blockIdx.x;
    const int lane = threadIdx.x & 63;
    const int w    = threadIdx.x >> 6;

    if (blk < 192) {                       // ---- normalize emb1 -> f32
        int row = blk * 4 + w;
        const float* r = emb1 + (size_t)row * D;
        float v[8]; float s = 0.f;
#pragma unroll
        for (int i = 0; i < 8; ++i) { v[i] = r[i * 64 + lane]; s += v[i] * v[i]; }
#pragma unroll
        for (int off = 32; off; off >>= 1) s += __shfl_xor(s, off);
        float inv = 1.f / fmaxf(sqrtf(s), 1e-12f);
        float* o = n1 + (size_t)row * D;
#pragma unroll
        for (int i = 0; i < 8; ++i) o[i * 64 + lane] = v[i] * inv;
    } else if (blk < 576) {                // ---- normalize emb2 -> bf16
        int row = (blk - 192) * 4 + w;
        const float* r = emb2 + (size_t)row * D;
        float v[8]; float s = 0.f;
#pragma unroll
        for (int i = 0; i < 8; ++i) { v[i] = r[i * 64 + lane]; s += v[i] * v[i]; }
#pragma unroll
        for (int off = 32; off; off >>= 1) s += __shfl_xor(s, off);
        float inv = 1.f / fmaxf(sqrtf(s), 1e-12f);
        ushort_t* o = n2h + (size_t)row * D;
#pragma unroll
        for (int i = 0; i < 8; ++i) o[i * 64 + lane] = f2bf(v[i] * inv);
    } else if (blk < 1088) {               // ---- cert2 layers 1,2 -> bf16
        int t = (blk - 576) * 256 + threadIdx.x;
        const float* s4 = cert2 + (size_t)NB2 * D + (size_t)t * 4;
        float4 v = *(const float4*)s4;
        uint2 o;
        o.x = (uint_t)f2bf(v.x) | ((uint_t)f2bf(v.y) << 16);
        o.y = (uint_t)f2bf(v.z) | ((uint_t)f2bf(v.w) << 16);
        *(uint2*)(c2h + (size_t)t * 4) = o;
    } else {                               // ---- top-3 per column
        int gw = (blk - 1088) * 4 + w;     // l*512 + e
        int l = gw >> 9;
        int e = gw & (D - 1);
        const float* base = links + (size_t)l * D * D + e;
        float v[8];
#pragma unroll
        for (int i = 0; i < 8; ++i) v[i] = base[(size_t)(i * 64 + lane) * D];
        float mv[3]; int mi[3];
        for (int k = 0; k < 3; ++k) {
            float lm = -1.f; int li = 0x7fffffff;
#pragma unroll
            for (int i = 0; i < 8; ++i)
                if (v[i] > lm) { lm = v[i]; li = i * 64 + lane; }
#pragma unroll
            for (int off = 32; off; off >>= 1) {
                float ov = __shfl_xor(lm, off);
                int oi = __shfl_xor(li, off);
                if (ov > lm || (ov == lm && oi < li)) { lm = ov; li = oi; }
            }
            mv[k] = lm; mi[k] = li;
            if (li < D && (li & 63) == lane) v[li >> 6] = -1.f;
        }
        if (lane == 0) {
            float invs = 1.f / (mv[0] + mv[1] + mv[2] + 1e-8f);
            uint_t f0 = (uint_t)mi[0] ^ (((uint_t)mi[0] >> 3) & 7u);
            uint_t f1 = (uint_t)mi[1] ^ (((uint_t)mi[1] >> 3) & 7u);
            uint_t f2 = (uint_t)mi[2] ^ (((uint_t)mi[2] >> 3) & 7u);
            pidx[gw] = f0 | (f1 << 9) | (f2 << 18);
            wval[(l * 3 + 0) * D + e] = mv[0] * invs;
            wval[(l * 3 + 1) * D + e] = mv[1] * invs;
            wval[(l * 3 + 2) * D + e] = mv[2] * invs;
        }
    }
}

// ================= gather-triple bank balance (LDS-staged, register counters) =================
__global__ __launch_bounds__(256) void balance_kernel(uint_t* __restrict__ pidx,
                                                      float* __restrict__ wval) {
    __shared__ uint_t sp[2 * D];          // 4 KB
    __shared__ float  sw[6 * D];          // 12 KB
    const int tid = threadIdx.x;

    // cooperative load: 1024 u32 (4/thread), 3072 f32 (12/thread)
    {
        uint4 v = *(const uint4*)(pidx + tid * 4);
        *(uint4*)(sp + tid * 4) = v;
#pragma unroll
        for (int k = 0; k < 3; ++k) {
            float4 f = *(const float4*)(wval + k * 1024 + tid * 4);
            *(float4*)(sw + k * 1024 + tid * 4) = f;
        }
    }
    __syncthreads();

    if (tid < 16) {
        const int l   = tid >> 3;
        const int w   = (tid >> 1) & 3;
        const int par = tid & 1;
        // 8 bank-group counters per gather position, bit-packed 8b each (registers!)
        unsigned long long cnt0 = 0, cnt1 = 0, cnt2 = 0;
        for (int j = 0; j < 64; ++j) {
            int e = w * 128 + par + j * 2;
            uint_t p = sp[l * D + e];
            uint_t sA = p & 511u, sB = (p >> 9) & 511u, sC = (p >> 18) & 511u;
            float wA = sw[(l*3+0)*D+e], wB = sw[(l*3+1)*D+e], wC = sw[(l*3+2)*D+e];
            uint_t b0 = sA, b1 = sB, b2 = sC;
            float  q0 = wA, q1 = wB, q2 = wC;
            int bc = 0x7fffffff;
#define TRY(x0,x1,x2,y0,y1,y2) { \
    int c = (int)((cnt0 >> (((x0) & 7u) * 8)) & 0xffu) + \
            (int)((cnt1 >> (((x1) & 7u) * 8)) & 0xffu) + \
            (int)((cnt2 >> (((x2) & 7u) * 8)) & 0xffu); \
    if (c < bc) { bc = c; b0 = x0; b1 = x1; b2 = x2; q0 = y0; q1 = y1; q2 = y2; } }
            TRY(sA, sB, sC, wA, wB, wC)
            TRY(sA, sC, sB, wA, wC, wB)
            TRY(sB, sA, sC, wB, wA, wC)
            TRY(sB, sC, sA, wB, wC, wA)
            TRY(sC, sA, sB, wC, wA, wB)
            TRY(sC, sB, sA, wC, wB, wA)
#undef TRY
            cnt0 += 1ull << ((b0 & 7u) * 8);
            cnt1 += 1ull << ((b1 & 7u) * 8);
            cnt2 += 1ull << ((b2 & 7u) * 8);
            sp[l * D + e] = b0 | (b1 << 9) | (b2 << 18);
            sw[(l*3+0)*D+e] = q0;
            sw[(l*3+1)*D+e] = q1;
            sw[(l*3+2)*D+e] = q2;
        }
    }
    __syncthreads();

    // cooperative store back
    {
        uint4 v = *(const uint4*)(sp + tid * 4);
        *(uint4*)(pidx + tid * 4) = v;
#pragma unroll
        for (int k = 0; k < 3; ++k) {
            float4 f = *(const float4*)(sw + k * 1024 + tid * 4);
            *(float4*)(wval + k * 1024 + tid * 4) = f;
        }
    }
}

// ================= fused main kernel =================
// block = (b, 32 n's); 4 waves split e; n batched by 4; 2-phase pipelined.
__global__ __launch_bounds__(256, 6) void avsl_main_kernel(
    const float* __restrict__ n1,      // (3,B1,D) f32 normalized emb1
    const ushort_t* __restrict__ n2h,  // (3,B2,D) bf16 normalized emb2
    const float* __restrict__ cert1,   // (3,B1,D) f32
    const ushort_t* __restrict__ c2h,  // (2,B2,D) bf16 cert2 layers 1,2
    const uint_t* __restrict__ pidx,   // (2,D) phi-swizzled, bank-balanced indices
    const float* __restrict__ wval,    // (2,3,D) matched weights
    const float* __restrict__ alpha,   // (2,D)
    const float* __restrict__ beta,    // (2,D)
    float* __restrict__ out)           // (B1,B2)
{
    __shared__ F4 vbuf[3 * D];         // [0..511]=v0 ping, [512..1023]=v0 pong, [1024..1535]=v1
    __shared__ float pbuf[16];
    const int tid  = threadIdx.x;
    const int lane = tid & 63;
    const int wid  = tid >> 6;
    const int b    = blockIdx.x >> 4;
    const int n0   = (blockIdx.x & 15) * 32;
    const int e0   = wid * 128 + lane * 2;     // lane owns e0, e0+1

    // ---- persistent per-e tables
    float2 a0  = *(const float2*)(n1 + (size_t)(0 * NB1 + b) * D + e0);
    float2 a1  = *(const float2*)(n1 + (size_t)(1 * NB1 + b) * D + e0);
    float2 a2  = *(const float2*)(n1 + (size_t)(2 * NB1 + b) * D + e0);
    float2 al1 = *(const float2*)(alpha + e0);
    float2 al2 = *(const float2*)(alpha + D + e0);
    float2 c11 = *(const float2*)(cert1 + (size_t)(1 * NB1 + b) * D + e0);
    float2 c12 = *(const float2*)(cert1 + (size_t)(2 * NB1 + b) * D + e0);
    float2 be1 = *(const float2*)(beta + e0);
    float2 be2 = *(const float2*)(beta + D + e0);
    const float acn1x = -al1.x * c11.x * LOG2E, acn1y = -al1.y * c11.y * LOG2E;
    const float acn2x = -al2.x * c12.x * LOG2E, acn2y = -al2.y * c12.y * LOG2E;
    const float btn1x = -be1.x * LOG2E, btn1y = -be1.y * LOG2E;
    const float btn2x = -be2.x * LOG2E, btn2y = -be2.y * LOG2E;

    float w1v[3][2], w2v[3][2];
#pragma unroll
    for (int k = 0; k < 3; ++k) {
        float2 t1 = *(const float2*)(wval + k * D + e0);
        float2 t2 = *(const float2*)(wval + (3 + k) * D + e0);
        w1v[k][0] = t1.x; w1v[k][1] = t1.y;
        w2v[k][0] = t2.x; w2v[k][1] = t2.y;
    }
    uint2 p1 = *(const uint2*)(pidx + e0);
    uint2 p2 = *(const uint2*)(pidx + D + e0);

    // hoisted LDS gather pointers (parity handled via [512] imm offset)
    const F4* q1a0 = &vbuf[p1.x & 511u];
    const F4* q1b0 = &vbuf[(p1.x >> 9) & 511u];
    const F4* q1c0 = &vbuf[(p1.x >> 18) & 511u];
    const F4* q1a1 = &vbuf[p1.y & 511u];
    const F4* q1b1 = &vbuf[(p1.y >> 9) & 511u];
    const F4* q1c1 = &vbuf[(p1.y >> 18) & 511u];
    const F4* q2a0 = &vbuf[1024 + (p2.x & 511u)];
    const F4* q2b0 = &vbuf[1024 + ((p2.x >> 9) & 511u)];
    const F4* q2c0 = &vbuf[1024 + ((p2.x >> 18) & 511u)];
    const F4* q2a1 = &vbuf[1024 + (p2.y & 511u)];
    const F4* q2b1 = &vbuf[1024 + ((p2.y >> 9) & 511u)];
    const F4* q2c1 = &vbuf[1024 + ((p2.y >> 18) & 511u)];
    const int sl0 = e0 ^ ((e0 >> 3) & 7);
    const int sl1 = (e0 + 1) ^ (((e0 + 1) >> 3) & 7);
    F4* qw0a = &vbuf[sl0];
    F4* qw0b = &vbuf[sl1];
    F4* qw1a = &vbuf[1024 + sl0];
    F4* qw1b = &vbuf[1024 + sl1];

    // stream pointers (advanced 4 rows per group)
    const ushort_t* pr0 = n2h + (size_t)(0 * NB2 + n0) * D + e0;
    const ushort_t* pr1 = n2h + (size_t)(1 * NB2 + n0) * D + e0;
    const ushort_t* pr2 = n2h + (size_t)(2 * NB2 + n0) * D + e0;
    const ushort_t* pc1 = c2h + (size_t)(0 * NB2 + n0) * D + e0;
    const ushort_t* pc2 = c2h + (size_t)(1 * NB2 + n0) * D + e0;

    // ---- prologue: loads for g=0, L0(0) -> v0[ping]
    uint_t r1c[4], c1c[4], r0c[4];
#pragma unroll
    for (int nn = 0; nn < 4; ++nn) {
        r0c[nn] = *(const uint_t*)(pr0 + nn * D);
        r1c[nn] = *(const uint_t*)(pr1 + nn * D);
        c1c[nn] = *(const uint_t*)(pc1 + nn * D);
    }
    {
        F4 v0a, v0b;
#pragma unroll
        for (int nn = 0; nn < 4; ++nn) {
            float d0 = a0.x - bflo(r0c[nn]);
            float d1 = a0.y - bfhi(r0c[nn]);
            v0a.c[nn] = d0 * d0;
            v0b.c[nn] = d1 * d1;
        }
        qw0a[0] = v0a;
        qw0b[0] = v0b;
    }
    __syncthreads();

#pragma unroll 2
    for (int g = 0; g < 8; ++g) {
        // ================= phase A =================
        if (g) {
            if (tid < 4)
                out[(size_t)b * NB2 + n0 + (g - 1) * 4 + tid] =
                    pbuf[tid] + pbuf[4 + tid] + pbuf[8 + tid] + pbuf[12 + tid];
        }
        // issue: r0 for g+1, r2/c2 for this g (overreads at g=7 land in next layer: in-bounds)
        uint_t r0n[4], r2c[4], c2c[4];
#pragma unroll
        for (int nn = 0; nn < 4; ++nn) {
            r0n[nn] = *(const uint_t*)(pr0 + (4 + nn) * D);
            r2c[nn] = *(const uint_t*)(pr2 + nn * D);
            c2c[nn] = *(const uint_t*)(pc2 + nn * D);
        }
        // L1: gather v0[g&1], blend, write v1
        {
            F4 gA0 = q1a0[(g & 1) * 512], gB0 = q1b0[(g & 1) * 512], gC0 = q1c0[(g & 1) * 512];
            F4 gA1 = q1a1[(g & 1) * 512], gB1 = q1b1[(g & 1) * 512], gC1 = q1c1[(g & 1) * 512];
            F4 o0, o1;
#pragma unroll
            for (int nn = 0; nn < 4; ++nn) {
                float rl = bflo(r1c[nn]), rh = bfhi(r1c[nn]);
                float cl = bflo(c1c[nn]), ch = bfhi(c1c[nn]);
                float gs0 = fmaf(w1v[0][0], gA0.c[nn], fmaf(w1v[1][0], gB0.c[nn], w1v[2][0] * gC0.c[nn]));
                float gs1 = fmaf(w1v[0][1], gA1.c[nn], fmaf(w1v[1][1], gB1.c[nn], w1v[2][1] * gC1.c[nn]));
                float P0 = __builtin_amdgcn_rcpf(1.f + __builtin_amdgcn_exp2f(fmaf(acn1x, cl, btn1x)));
                float P1 = __builtin_amdgcn_rcpf(1.f + __builtin_amdgcn_exp2f(fmaf(acn1y, ch, btn1y)));
                float d0 = a1.x - rl, d1 = a1.y - rh;
                o0.c[nn] = gs0 + P0 * (d0 * d0 - gs0);
                o1.c[nn] = gs1 + P1 * (d1 * d1 - gs1);
            }
            qw1a[0] = o0;
            qw1b[0] = o1;
        }
        __syncthreads();

        // ================= phase B =================
        // issue: r1/c1 for g+1 (overread at g=7 in-bounds)
        uint_t r1n[4], c1n[4];
#pragma unroll
        for (int nn = 0; nn < 4; ++nn) {
            r1n[nn] = *(const uint_t*)(pr1 + (4 + nn) * D);
            c1n[nn] = *(const uint_t*)(pc1 + (4 + nn) * D);
        }
        // L2: gather v1, blend, accumulate
        F4 acc;
        {
            F4 gA0 = q2a0[0], gB0 = q2b0[0], gC0 = q2c0[0];
            F4 gA1 = q2a1[0], gB1 = q2b1[0], gC1 = q2c1[0];
#pragma unroll
            for (int nn = 0; nn < 4; ++nn) {
                float rl = bflo(r2c[nn]), rh = bfhi(r2c[nn]);
                float cl = bflo(c2c[nn]), ch = bfhi(c2c[nn]);
                float gs0 = fmaf(w2v[0][0], gA0.c[nn], fmaf(w2v[1][0], gB0.c[nn], w2v[2][0] * gC0.c[nn]));
                float gs1 = fmaf(w2v[0][1], gA1.c[nn], fmaf(w2v[1][1], gB1.c[nn], w2v[2][1] * gC1.c[nn]));
                float P0 = __builtin_amdgcn_rcpf(1.f + __builtin_amdgcn_exp2f(fmaf(acn2x, cl, btn2x)));
                float P1 = __builtin_amdgcn_rcpf(1.f + __builtin_amdgcn_exp2f(fmaf(acn2y, ch, btn2y)));
                float d0 = a2.x - rl, d1 = a2.y - rh;
                acc.c[nn] = (gs0 + P0 * (d0 * d0 - gs0)) + (gs1 + P1 * (d1 * d1 - gs1));
            }
        }
        // L0 for g+1 -> v0[(g+1)&1]
        {
            F4 v0a, v0b;
#pragma unroll
            for (int nn = 0; nn < 4; ++nn) {
                float d0 = a0.x - bflo(r0n[nn]);
                float d1 = a0.y - bfhi(r0n[nn]);
                v0a.c[nn] = d0 * d0;
                v0b.c[nn] = d1 * d1;
            }
            qw0a[((g + 1) & 1) * 512] = v0a;
            qw0b[((g + 1) & 1) * 512] = v0b;
        }
        // wave reduction: DPP split butterfly (VALU) + xor16 swizzle + xor32
        {
            float c0 = acc.c[0], c1 = acc.c[1], c2 = acc.c[2], c3 = acc.c[3];
            float pA = DPPF(c0, 0xB1);   // quad_perm [1,0,3,2]  (xor 1)
            float pB = DPPF(c1, 0xB1);
            float pC = DPPF(c2, 0xB1);
            float pD = DPPF(c3, 0xB1);
            float u0, u1;
            if (lane & 1) { u0 = c1 + pB; u1 = c3 + pD; }
            else          { u0 = c0 + pA; u1 = c2 + pC; }
            float q0 = DPPF(u0, 0x4E);   // quad_perm [2,3,0,1]  (xor 2)
            float q1 = DPPF(u1, 0x4E);
            float v = (lane & 2) ? (u1 + q1) : (u0 + q0);   // holds nn = lane&3
            v += DPPF(v, 0x124);          // row_ror:4
            v += DPPF(v, 0x128);          // row_ror:8
            v += __int_as_float(__builtin_amdgcn_ds_swizzle(__float_as_int(v), 0x401F)); // xor 16
            v += __shfl_xor(v, 32);
            if (lane < 4) pbuf[wid * 4 + lane] = v;
        }
        __syncthreads();

        // rotate prefetched data / advance pointers
#pragma unroll
        for (int nn = 0; nn < 4; ++nn) { r1c[nn] = r1n[nn]; c1c[nn] = c1n[nn]; }
        pr0 += 4 * D; pr1 += 4 * D; pr2 += 4 * D; pc1 += 4 * D; pc2 += 4 * D;
    }

    // epilogue: out-write for g=7
    if (tid < 4)
        out[(size_t)b * NB2 + n0 + 28 + tid] =
            pbuf[tid] + pbuf[4 + tid] + pbuf[8 + tid] + pbuf[12 + tid];
}

extern "C" void kernel_launch(void* const* d_in, const int* in_sizes, int n_in,
                              void* d_out, int out_size, void* d_ws, size_t ws_size,
                              hipStream_t stream) {
    const float* emb1  = (const float*)d_in[0];  // (3,256,512)
    const float* cert1 = (const float*)d_in[1];  // (3,256,512)
    const float* emb2  = (const float*)d_in[2];  // (3,512,512)
    const float* cert2 = (const float*)d_in[3];  // (3,512,512)
    const float* links = (const float*)d_in[4];  // (2,512,512)
    const float* alpha = (const float*)d_in[5];  // (2,512)
    const float* beta  = (const float*)d_in[6];  // (2,512)
    float* out = (float*)d_out;                  // (256,512)

    float* n1      = (float*)d_ws;                      // 3*256*512 f32
    ushort_t* n2h  = (ushort_t*)(n1 + 3 * NB1 * D);     // 3*512*512 bf16
    ushort_t* c2h  = n2h + 3 * NB2 * D;                 // 2*512*512 bf16
    uint_t* pidx   = (uint_t*)(c2h + 2 * NB2 * D);      // 2*512 u32
    float* wval    = (float*)(pidx + 2 * D);            // 2*3*512 f32

    hipLaunchKernelGGL(prep_kernel, dim3(1344), dim3(256), 0, stream,
                       emb1, emb2, cert2, links, n1, n2h, c2h, pidx, wval);
    hipLaunchKernelGGL(balance_kernel, dim3(1), dim3(256), 0, stream, pidx, wval);
    hipLaunchKernelGGL(avsl_main_kernel, dim3(4096), dim3(256), 0, stream,
                       n1, n2h, cert1, c2h, pidx, wval, alpha, beta, out);
}